// Round 3
// baseline (1217.472 us; speedup 1.0000x reference)
//
#include <hip/hip_runtime.h>

#define NNET 32
#define NUNITS 2048
#define NEXC 1638
#define NINH 410

// ---------------------------------------------------------------------------
// Jobs 1-4: acc[n,q] += sum_p W[n,p,q] * r[n,p]  (contraction over p, q contiguous)
// float2 version: thread t owns columns q = qb*512 + 2t, 2t+1. Q is even and all
// row starts are even -> 8B-aligned float2 loads, coalesced 512B/wave-instr.
// ---------------------------------------------------------------------------
__device__ __forceinline__ void col_matvec2(const float* __restrict__ W,
                                            const float* __restrict__ r,
                                            float* __restrict__ acc,
                                            int rel_blk,
                                            int P, int Q, int QB, int PB, int PCH,
                                            int qoff, int vecoff) {
    int n   = rel_blk / (QB * PB);
    int rem = rel_blk % (QB * PB);
    int qb  = rem / PB;
    int pb  = rem % PB;

    int q  = qb * 512 + 2 * (int)threadIdx.x;
    int p0 = pb * PCH;
    int len = min(PCH, P - p0);

    __shared__ float s_r[256];            // PCH <= 205
    if ((int)threadIdx.x < len)
        s_r[threadIdx.x] = r[n * NUNITS + vecoff + p0 + threadIdx.x];
    __syncthreads();

    if (q >= Q) return;                   // Q even: pairs never straddle

    const float2* Wp  = (const float2*)(W + ((size_t)n * P + p0) * Q + q);
    size_t       step = (size_t)(Q >> 1); // float2 stride between rows
    float ax = 0.f, ay = 0.f;
    int p = 0;
    for (; p + 4 <= len; p += 4) {
        float2 w0 = Wp[(size_t)(p + 0) * step];
        float2 w1 = Wp[(size_t)(p + 1) * step];
        float2 w2 = Wp[(size_t)(p + 2) * step];
        float2 w3 = Wp[(size_t)(p + 3) * step];
        ax += w0.x * s_r[p] + w1.x * s_r[p + 1] + w2.x * s_r[p + 2] + w3.x * s_r[p + 3];
        ay += w0.y * s_r[p] + w1.y * s_r[p + 1] + w2.y * s_r[p + 2] + w3.y * s_r[p + 3];
    }
    for (; p < len; ++p) {
        float2 w = Wp[(size_t)p * step];
        ax += w.x * s_r[p];
        ay += w.y * s_r[p];
    }

    atomicAdd(&acc[n * NUNITS + qoff + q],     ax);
    atomicAdd(&acc[n * NUNITS + qoff + q + 1], ay);
}

// ---------------------------------------------------------------------------
// Job 5: inter_inh[i,a] = sum_{j,b} W_inter[i,j,a,b] * r[i, NEXC+b]
// Block = (i, j, half): reads a fully contiguous 205x410-float chunk (336 KB).
// 4 waves round-robin rows; lanes stride float2 along b; shfl-reduce; 1 atomic/row.
// ---------------------------------------------------------------------------
__device__ __forceinline__ void inter_ij(const float* __restrict__ Wint,
                                         const float* __restrict__ r,
                                         float* __restrict__ acc,
                                         int rel_blk) {
    int i    = rel_blk >> 6;          // /64
    int j    = (rel_blk >> 1) & 31;
    int half = rel_blk & 1;

    __shared__ float s_ri[NINH];
    for (int t = threadIdx.x; t < NINH; t += 256)
        s_ri[t] = r[i * NUNITS + NEXC + t];   // NB: einsum 'ijab,ib->ia' -> r of network i
    __syncthreads();

    int wave = threadIdx.x >> 6;
    int lane = threadIdx.x & 63;

    const float* plane = Wint + (size_t)(i * NNET + j) * NINH * NINH;
    int a0 = half * 205;
    int a1 = a0 + 205;                 // 410 = 2*205
    for (int a = a0 + wave; a < a1; a += 4) {
        const float2* row2 = (const float2*)(plane + (size_t)a * NINH);
        float s = 0.f;
        for (int b2 = lane; b2 < NINH / 2; b2 += 64) {   // 205 float2s
            float2 w = row2[b2];
            s += w.x * s_ri[2 * b2] + w.y * s_ri[2 * b2 + 1];
        }
        for (int off = 32; off; off >>= 1)
            s += __shfl_down(s, off, 64);
        if (lane == 0)
            atomicAdd(&acc[i * NUNITS + NEXC + a], s);
    }
}

// ---------------------------------------------------------------------------
// Fused kernel. Flat grid, 3648 blocks:
//   [0,1024)     W_ee: QB=4, PB=8
//   [1024,1280)  W_ie: QB=4, PB=2
//   [1280,1536)  W_ei: QB=1, PB=8
//   [1536,1600)  W_ii: QB=1, PB=2
//   [1600,3648)  W_inter: 32*32*2 contiguous half-planes
// ---------------------------------------------------------------------------
__global__ __launch_bounds__(256) void fused_matvec(
    const float* __restrict__ Wee, const float* __restrict__ Wei,
    const float* __restrict__ Wie, const float* __restrict__ Wii,
    const float* __restrict__ Wint,
    const float* __restrict__ r, float* __restrict__ acc) {
    int blk = blockIdx.x;
    if (blk < 1024) {
        col_matvec2(Wee, r, acc, blk,        1638, 1638, 4, 8, 205, 0,    0);
    } else if (blk < 1280) {
        col_matvec2(Wie, r, acc, blk - 1024,  410, 1638, 4, 2, 205, 0,    NEXC);
    } else if (blk < 1536) {
        col_matvec2(Wei, r, acc, blk - 1280, 1638,  410, 1, 8, 205, NEXC, 0);
    } else if (blk < 1600) {
        col_matvec2(Wii, r, acc, blk - 1536,  410,  410, 1, 2, 205, NEXC, NEXC);
    } else {
        inter_ij(Wint, r, acc, blk - 1600);
    }
}

// ---------------------------------------------------------------------------
// Finalize: r_new = 0.9*r + 0.1*relu(acc + unit_input)
// ---------------------------------------------------------------------------
__global__ __launch_bounds__(256) void finalize_kernel(
    const float* __restrict__ r, const float* __restrict__ uin,
    const float* __restrict__ acc, float* __restrict__ out) {
    int idx = blockIdx.x * 256 + threadIdx.x;
    if (idx < NNET * NUNITS) {
        float total = acc[idx] + uin[idx];
        float phi = fmaxf(total, 0.f);
        out[idx] = 0.9f * r[idx] + 0.1f * phi;
    }
}

extern "C" void kernel_launch(void* const* d_in, const int* in_sizes, int n_in,
                              void* d_out, int out_size, void* d_ws, size_t ws_size,
                              hipStream_t stream) {
    const float* unit_input = (const float*)d_in[0];
    const float* r          = (const float*)d_in[1];
    const float* W_ee       = (const float*)d_in[2];
    const float* W_ei       = (const float*)d_in[3];
    const float* W_ie       = (const float*)d_in[4];
    const float* W_ii       = (const float*)d_in[5];
    const float* W_inter    = (const float*)d_in[6];
    float* out = (float*)d_out;
    float* acc = (float*)d_ws;  // 32*2048 floats = 256 KB

    hipMemsetAsync(acc, 0, NNET * NUNITS * sizeof(float), stream);

    fused_matvec<<<3648, 256, 0, stream>>>(W_ee, W_ei, W_ie, W_ii, W_inter, r, acc);

    finalize_kernel<<<(NNET * NUNITS + 255) / 256, 256, 0, stream>>>(r, unit_input, acc, out);
}